// Round 6
// baseline (275.206 us; speedup 1.0000x reference)
//
#include <hip/hip_runtime.h>

#define THREADS 256
#define IPB 8   // images per block; grid = batch/8 = 1024

typedef _Float16 f16;
typedef _Float16 f16x8 __attribute__((ext_vector_type(8)));
typedef float f32x16 __attribute__((ext_vector_type(16)));

// p1 layout: [img][iy 12][ix 12][ic 16] f16. Row stride 400B (384 data + 16 pad
// to break the 128B bank cycle); img stride 4800B. ic 10..15 written as zeros.
#define P1_ROW 400
#define P1_IMG 4800

// LDS: p1 38400 + p2 8*321*4 = 10272 + h1 8*51*4 = 1632 -> 50304B, 3 blocks/CU.
__global__ __launch_bounds__(THREADS, 3)
void lenet_one(const float* __restrict__ x,
               const float* __restrict__ w1, const float* __restrict__ b1,
               const float* __restrict__ w2, const float* __restrict__ b2,
               const float* __restrict__ wl1, const float* __restrict__ bl1,
               const float* __restrict__ wl2, const float* __restrict__ bl2,
               float* __restrict__ out, int batch)
{
    __shared__ __align__(16) unsigned char p1c[IPB * P1_IMG];
    __shared__ float p2[8 * 321];          // [img][320 pad 321], idx oc*16+py*4+px
    __shared__ float h1[8 * 51];           // [img][50 pad 51]

    const int tid = threadIdx.x;
    const int img = tid & 7;
    const int imgg = min(blockIdx.x * IPB + img, batch - 1);

    // ---------- conv1 (1->10ch) + bias + relu + pool; weights via s_load ------
    {
        const int grp = tid >> 3;                 // 0..31 position groups
        const float* xim = x + (size_t)imgg * 784;
        for (int pq = grp; pq < 144; pq += 32) {
            const int py = pq / 12, px = pq % 12;
            const float* xb = xim + (2 * py) * 28 + 2 * px;
            float win[36];                        // 6x6 input window, regs
            #pragma unroll
            for (int r = 0; r < 6; ++r)
                #pragma unroll
                for (int cc = 0; cc < 6; ++cc)
                    win[r * 6 + cc] = xb[r * 28 + cc];
            float ch[10];
            for (int c = 0; c < 10; ++c) {        // win reused across all 10 ch
                float a00 = 0.f, a01 = 0.f, a10 = 0.f, a11 = 0.f;
                #pragma unroll
                for (int ky = 0; ky < 5; ++ky)
                    #pragma unroll
                    for (int kx = 0; kx < 5; ++kx) {
                        const float wv = w1[c * 25 + ky * 5 + kx];  // uniform
                        a00 += win[ky * 6 + kx]           * wv;
                        a01 += win[ky * 6 + kx + 1]       * wv;
                        a10 += win[(ky + 1) * 6 + kx]     * wv;
                        a11 += win[(ky + 1) * 6 + kx + 1] * wv;
                    }
                const float m = fmaxf(fmaxf(a00, a01), fmaxf(a10, a11));
                ch[c] = fmaxf(m + b1[c], 0.f);
            }
            // pack 10 ch + 6 zeros as f16 -> two b128 stores (channel-last)
            f16x8 v0, v1;
            #pragma unroll
            for (int j = 0; j < 8; ++j) v0[j] = (f16)ch[j];
            v1[0] = (f16)ch[8]; v1[1] = (f16)ch[9];
            #pragma unroll
            for (int j = 2; j < 8; ++j) v1[j] = (f16)0.f;
            unsigned char* dst = p1c + img * P1_IMG + py * P1_ROW + px * 32;
            *(f16x8*)(dst)      = v0;
            *(f16x8*)(dst + 16) = v1;
        }
    }

    // ---------- conv2 A-fragments: w2 -> 25 x f16x8 in VGPRs ------------------
    // k = s*16 + h*8 + j  <->  (pos25 = s = ky*5+kx, ic = h*8+j); 0-pad m>=20,ic>=10
    const int lane = tid & 63;
    const int wv_ = tid >> 6;                 // wave id 0..3
    const int cM = lane & 31, hK = lane >> 5;
    f16x8 af[25];
    {
        #pragma unroll
        for (int s = 0; s < 25; ++s) {
            f16x8 a;
            #pragma unroll
            for (int j = 0; j < 8; ++j) {
                const int ic = hK * 8 + j;
                const float v = (cM < 20 && ic < 10) ? w2[(cM * 10 + ic) * 25 + s]
                                                     : 0.f;
                a[j] = (f16)v;
            }
            af[s] = a;
        }
    }
    __syncthreads();

    // ---------- conv2 via mfma_f32_32x32x16_f16 + pool + relu -> p2 -----------
    // Ntile t = (img, oy-half). B[n=col][k]: col c -> oy=4*h2+(c>>3), ox=c&7.
    {
        const int cy = cM >> 3, cx = cM & 7;
        #pragma unroll 1
        for (int t = wv_ * 4; t < wv_ * 4 + 4; ++t) {
            const int im = t >> 1, h2 = t & 1;
            const int oy = 4 * h2 + cy;
            const unsigned char* bbase =
                p1c + im * P1_IMG + oy * P1_ROW + cx * 32 + hK * 16;
            f32x16 acc;
            #pragma unroll
            for (int r = 0; r < 16; ++r) acc[r] = 0.f;
            #pragma unroll
            for (int s = 0; s < 25; ++s) {
                const int ky = s / 5, kx = s % 5;
                const f16x8 b = *(const f16x8*)(bbase + ky * P1_ROW + kx * 32);
                acc = __builtin_amdgcn_mfma_f32_32x32x16_f16(af[s], b, acc, 0, 0, 0);
            }
            // epilogue: rows m=(r&3)+8*(r>>2)+4*hK, col pool via shfl_xor 1,8
            #pragma unroll
            for (int r = 0; r < 16; ++r) {
                const int m = (r & 3) + 8 * (r >> 2) + 4 * hK;
                if (m < 20) {
                    float v = acc[r];
                    v = fmaxf(v, __shfl_xor(v, 1, 64));
                    v = fmaxf(v, __shfl_xor(v, 8, 64));
                    if ((lane & 9) == 0) {   // c even, cy even: owner lane
                        const int py = 2 * h2 + (cM >> 4);
                        const int px = cx >> 1;
                        p2[im * 321 + m * 16 + py * 4 + px] =
                            fmaxf(v + b2[m], 0.f);
                    }
                }
            }
        }
    }
    __syncthreads();

    // ---------- fc1: 320->50 relu; lane=k, coalesced wl1, shuffle reduce ------
    {
        const int hbase = wv_ * 13;
        const int nh = (wv_ == 3) ? 11 : 13;       // 13+13+13+11 = 50
        for (int hi = 0; hi < nh; ++hi) {
            const int h = hbase + hi;
            float wrow[5];
            #pragma unroll
            for (int j = 0; j < 5; ++j)          // coalesced: k = lane + 64j
                wrow[j] = wl1[h * 320 + lane + 64 * j];
            for (int im = 0; im < 8; ++im) {     // weight regs reused across imgs
                float s = 0.f;
                #pragma unroll
                for (int j = 0; j < 5; ++j)
                    s += p2[im * 321 + lane + 64 * j] * wrow[j];
                #pragma unroll
                for (int off = 32; off; off >>= 1)
                    s += __shfl_xor(s, off, 64);
                if (lane == 0)
                    h1[im * 51 + h] = fmaxf(s + bl1[h], 0.f);
            }
        }
    }
    __syncthreads();

    // ---------- fc2: 50->10 ---------------------------------------------------
    if (tid < 80) {
        const int im = tid / 10, o = tid % 10;
        const int imgo = min(blockIdx.x * IPB + im, batch - 1);
        float a = bl2[o];
        #pragma unroll
        for (int h = 0; h < 50; ++h)
            a += h1[im * 51 + h] * wl2[o * 50 + h];
        out[(size_t)imgo * 10 + o] = a;          // tid 0..79 -> coalesced
    }
}

extern "C" void kernel_launch(void* const* d_in, const int* in_sizes, int n_in,
                              void* d_out, int out_size, void* d_ws, size_t ws_size,
                              hipStream_t stream) {
    const float* x   = (const float*)d_in[0];
    const float* w1  = (const float*)d_in[1];
    const float* b1  = (const float*)d_in[2];
    const float* w2  = (const float*)d_in[3];
    const float* b2  = (const float*)d_in[4];
    const float* wl1 = (const float*)d_in[5];
    const float* bl1 = (const float*)d_in[6];
    const float* wl2 = (const float*)d_in[7];
    const float* bl2 = (const float*)d_in[8];
    float* out = (float*)d_out;

    const int batch = in_sizes[0] / 784;  // 8192
    const int grid = (batch + IPB - 1) / IPB;
    lenet_one<<<grid, THREADS, 0, stream>>>(x, w1, b1, w2, b2, wl1, bl1, wl2, bl2,
                                            out, batch);
}

// Round 7
// 228.590 us; speedup vs baseline: 1.2039x; 1.2039x over previous
//
#include <hip/hip_runtime.h>

#define THREADS 256
#define IPB 8   // images per block; grid = batch/8 = 1024

typedef _Float16 f16;
typedef _Float16 f16x8 __attribute__((ext_vector_type(8)));
typedef float f32x16 __attribute__((ext_vector_type(16)));

// p1 layout: [img][iy 12][ix 12][ic 16] f16. Row stride 400B; final row unpadded
// so img stride = 11*400+384 = 4784B. ic 10..15 written as zeros (K-pad).
#define P1_ROW 400
#define P1_IMG 4784

// LDS: p1c 38272 + union(af 16000 | p2 10272 + h1 1632) = 54272 B
//    = exactly 106 x 512B granules -> 3 blocks/CU (162816 <= 163840).
__global__ __launch_bounds__(THREADS, 3)
void lenet_one(const float* __restrict__ x,
               const float* __restrict__ w1, const float* __restrict__ b1,
               const float* __restrict__ w2, const float* __restrict__ b2,
               const float* __restrict__ wl1, const float* __restrict__ bl1,
               const float* __restrict__ wl2, const float* __restrict__ bl2,
               float* __restrict__ out, int batch)
{
    __shared__ __align__(16) unsigned char p1c[IPB * P1_IMG];
    __shared__ union U {
        f16 af[25 * 40 * 8];   // A-fragments [s][oc20*2+hK], 16B each; 16000 B
        struct { float p2[8 * 321]; float h1[8 * 51]; } s;  // after-MFMA phase
    } u;

    const int tid = threadIdx.x;
    const int lane = tid & 63;
    const int wv_ = tid >> 6;                 // wave id 0..3
    const int cM = lane & 31, hK = lane >> 5; // MFMA A: row m=cM, K-half hK
    const int img = tid & 7;
    const int imgg = min(blockIdx.x * IPB + img, batch - 1);

    // ---------- conv1 (1->10ch) + bias + relu + pool; weights via s_load ------
    {
        const int grp = tid >> 3;                 // 0..31 position groups
        const float* xim = x + (size_t)imgg * 784;
        for (int pq = grp; pq < 144; pq += 32) {
            const int py = pq / 12, px = pq % 12;
            const float* xb = xim + (2 * py) * 28 + 2 * px;
            float win[36];                        // 6x6 input window, regs
            #pragma unroll
            for (int r = 0; r < 6; ++r)
                #pragma unroll
                for (int cc = 0; cc < 6; ++cc)
                    win[r * 6 + cc] = xb[r * 28 + cc];
            float ch[10];
            for (int c = 0; c < 10; ++c) {        // win reused across all 10 ch
                float a00 = 0.f, a01 = 0.f, a10 = 0.f, a11 = 0.f;
                #pragma unroll
                for (int ky = 0; ky < 5; ++ky)
                    #pragma unroll
                    for (int kx = 0; kx < 5; ++kx) {
                        const float wv = w1[c * 25 + ky * 5 + kx];  // uniform
                        a00 += win[ky * 6 + kx]           * wv;
                        a01 += win[ky * 6 + kx + 1]       * wv;
                        a10 += win[(ky + 1) * 6 + kx]     * wv;
                        a11 += win[(ky + 1) * 6 + kx + 1] * wv;
                    }
                const float m = fmaxf(fmaxf(a00, a01), fmaxf(a10, a11));
                ch[c] = fmaxf(m + b1[c], 0.f);
            }
            f16x8 v0, v1;
            #pragma unroll
            for (int j = 0; j < 8; ++j) v0[j] = (f16)ch[j];
            v1[0] = (f16)ch[8]; v1[1] = (f16)ch[9];
            #pragma unroll
            for (int j = 2; j < 8; ++j) v1[j] = (f16)0.f;   // K-pad zeros
            unsigned char* dst = p1c + img * P1_IMG + py * P1_ROW + px * 32;
            *(f16x8*)(dst)      = v0;
            *(f16x8*)(dst + 16) = v1;
        }
    }

    // ---------- stage conv2 A-fragments (weights) into LDS --------------------
    // entry e = (s, oc, hK): 8 f16 = w2[(oc*10 + hK*8+j)*25 + s], 0 for ic>=10
    for (int e = tid; e < 1000; e += THREADS) {
        const int s = e / 40;
        const int r = e - s * 40;
        const int oc = r >> 1, h = r & 1;
        f16x8 a;
        #pragma unroll
        for (int j = 0; j < 8; ++j) {
            const int ic = h * 8 + j;
            a[j] = (f16)(ic < 10 ? w2[(oc * 10 + ic) * 25 + s] : 0.f);
        }
        *(f16x8*)&u.af[e * 8] = a;
    }
    __syncthreads();

    // ---------- conv2 via mfma_f32_32x32x16_f16, s-outer, 4 tiles/wave --------
    const int cy = cM >> 3, cx = cM & 7;
    const int afoff = ((cM < 20 ? cM : 19) * 2 + hK) * 8;  // clamp: rows>=20 unused
    int bb[4];
    #pragma unroll
    for (int q = 0; q < 4; ++q) {
        const int t = wv_ * 4 + q, im = t >> 1, h2 = t & 1;
        bb[q] = im * P1_IMG + (4 * h2 + cy) * P1_ROW + cx * 32 + hK * 16;
    }
    f32x16 acc[4];
    #pragma unroll
    for (int q = 0; q < 4; ++q)
        #pragma unroll
        for (int r = 0; r < 16; ++r) acc[q][r] = 0.f;
    #pragma unroll 1
    for (int ky = 0; ky < 5; ++ky) {
        #pragma unroll
        for (int kx = 0; kx < 5; ++kx) {
            const f16x8 a = *(const f16x8*)&u.af[(ky * 5 + kx) * 320 + afoff];
            #pragma unroll
            for (int q = 0; q < 4; ++q) {
                const f16x8 b =
                    *(const f16x8*)(p1c + bb[q] + ky * P1_ROW + kx * 32);
                acc[q] = __builtin_amdgcn_mfma_f32_32x32x16_f16(a, b, acc[q],
                                                                0, 0, 0);
            }
        }
    }
    __syncthreads();   // af & p1c dead -> union may flip to p2/h1

    // ---------- epilogue: pool(shfl 1,8) + bias + relu -> u.s.p2 --------------
    #pragma unroll
    for (int q = 0; q < 4; ++q) {
        const int t = wv_ * 4 + q, im = t >> 1, h2 = t & 1;
        #pragma unroll
        for (int r = 0; r < 16; ++r) {
            const int m = (r & 3) + 8 * (r >> 2) + 4 * hK;
            float v = acc[q][r];
            v = fmaxf(v, __shfl_xor(v, 1, 64));
            v = fmaxf(v, __shfl_xor(v, 8, 64));
            if (m < 20 && (lane & 9) == 0) {
                const int py = 2 * h2 + (cM >> 4), px = cx >> 1;
                u.s.p2[im * 321 + m * 16 + py * 4 + px] = fmaxf(v + b2[m], 0.f);
            }
        }
    }
    __syncthreads();

    // ---------- fc1: 320->50 relu; lane=k, coalesced wl1, shuffle reduce ------
    {
        const int hbase = wv_ * 13;
        const int nh = (wv_ == 3) ? 11 : 13;       // 13+13+13+11 = 50
        for (int hi = 0; hi < nh; ++hi) {
            const int h = hbase + hi;
            float wrow[5];
            #pragma unroll
            for (int j = 0; j < 5; ++j)          // coalesced: k = lane + 64j
                wrow[j] = wl1[h * 320 + lane + 64 * j];
            for (int im = 0; im < 8; ++im) {     // weight regs reused across imgs
                float s = 0.f;
                #pragma unroll
                for (int j = 0; j < 5; ++j)
                    s += u.s.p2[im * 321 + lane + 64 * j] * wrow[j];
                #pragma unroll
                for (int off = 32; off; off >>= 1)
                    s += __shfl_xor(s, off, 64);
                if (lane == 0)
                    u.s.h1[im * 51 + h] = fmaxf(s + bl1[h], 0.f);
            }
        }
    }
    __syncthreads();

    // ---------- fc2: 50->10 ---------------------------------------------------
    if (tid < 80) {
        const int im = tid / 10, o = tid % 10;
        const int imgo = min(blockIdx.x * IPB + im, batch - 1);
        float a = bl2[o];
        #pragma unroll
        for (int h = 0; h < 50; ++h)
            a += u.s.h1[im * 51 + h] * wl2[o * 50 + h];
        out[(size_t)imgo * 10 + o] = a;          // tid 0..79 -> coalesced
    }
}

extern "C" void kernel_launch(void* const* d_in, const int* in_sizes, int n_in,
                              void* d_out, int out_size, void* d_ws, size_t ws_size,
                              hipStream_t stream) {
    const float* x   = (const float*)d_in[0];
    const float* w1  = (const float*)d_in[1];
    const float* b1  = (const float*)d_in[2];
    const float* w2  = (const float*)d_in[3];
    const float* b2  = (const float*)d_in[4];
    const float* wl1 = (const float*)d_in[5];
    const float* bl1 = (const float*)d_in[6];
    const float* wl2 = (const float*)d_in[7];
    const float* bl2 = (const float*)d_in[8];
    float* out = (float*)d_out;

    const int batch = in_sizes[0] / 784;  // 8192
    const int grid = (batch + IPB - 1) / IPB;
    lenet_one<<<grid, THREADS, 0, stream>>>(x, w1, b1, w2, b2, wl1, bl1, wl2, bl2,
                                            out, batch);
}

// Round 9
// 176.487 us; speedup vs baseline: 1.5594x; 1.2952x over previous
//
#include <hip/hip_runtime.h>

#define THREADS 256
#define IPB 4   // images per block; grid = batch/4 = 2048

typedef _Float16 f16;
typedef _Float16 f16x2 __attribute__((ext_vector_type(2)));
typedef _Float16 f16x8 __attribute__((ext_vector_type(8)));
typedef float f32x16 __attribute__((ext_vector_type(16)));
typedef unsigned int uint;

__device__ __forceinline__ f16x2 pkrtz(float a, float b) {
    return __builtin_bit_cast(f16x2, __builtin_amdgcn_cvt_pkrtz(a, b));
}

// p1 layout: [img][iy 12][ix 12][ic 16] f16. Row stride 400B; final row unpadded
// so img stride = 11*400+384 = 4784B. ic 10..15 written as zeros (K-pad).
#define P1_ROW 400
#define P1_IMG 4784

// ---- setup: pack w1 as duplicated f16 pairs so main kernel s_loads them ----
__global__ void pack_w1(const float* __restrict__ w1, uint* __restrict__ w1pk) {
    const int i = threadIdx.x;
    if (i < 250) {
        f16 h = (f16)w1[i];
        const unsigned short u = __builtin_bit_cast(unsigned short, h);
        w1pk[i] = (uint)u | ((uint)u << 16);
    }
}

// LDS: p1c 4*4784=19136 + union(af 16000 | p2 4*321*4 + h1 4*51*4) = 35136 B
// -> 4 blocks/CU (16 waves/CU).
__global__ __launch_bounds__(THREADS, 4)
void lenet_one(const float* __restrict__ x,
               const uint* __restrict__ w1pk, const float* __restrict__ b1,
               const float* __restrict__ w2, const float* __restrict__ b2,
               const float* __restrict__ wl1, const float* __restrict__ bl1,
               const float* __restrict__ wl2, const float* __restrict__ bl2,
               float* __restrict__ out, int batch)
{
    __shared__ __align__(16) unsigned char p1c[IPB * P1_IMG];
    __shared__ union U {
        f16 af[25 * 40 * 8];   // A-fragments [s][oc20*2+hK], 16B each; 16000 B
        struct { float p2[IPB * 321]; float h1[IPB * 51]; } s;
    } u;

    const int tid = threadIdx.x;
    const int lane = tid & 63;
    const int wv_ = tid >> 6;                 // wave id 0..3
    const int cM = lane & 31, hK = lane >> 5; // MFMA A: row m=cM, K-half hK
    const int img = tid & 3;
    const int imgg = min(blockIdx.x * IPB + img, batch - 1);

    // ---------- conv1 (1->10ch) packed f16 + bias + relu + pool ---------------
    {
        const int grp = tid >> 2;                 // 0..63 position groups
        const float* xim = x + (size_t)imgg * 784;
        for (int pq = grp; pq < 144; pq += 64) {
            const int py = pq / 12, px = pq % 12;
            const float* xb = xim + (2 * py) * 28 + 2 * px;
            float win[36];                        // 6x6 input window
            #pragma unroll
            for (int r = 0; r < 6; ++r)
                #pragma unroll
                for (int cc = 0; cc < 6; ++cc)
                    win[r * 6 + cc] = xb[r * 28 + cc];
            // shifted pairs pr[r][c] = (win[r][c], win[r][c+1]), built once,
            // reused by all 10 channels; v_cvt_pkrtz = 1 op each.
            f16x2 pr[30];
            #pragma unroll
            for (int r = 0; r < 6; ++r)
                #pragma unroll
                for (int cc = 0; cc < 5; ++cc)
                    pr[r * 5 + cc] = pkrtz(win[r * 6 + cc], win[r * 6 + cc + 1]);
            f16 ch[10];
            #pragma unroll
            for (int c = 0; c < 10; ++c) {
                f16x2 accT = {(f16)0.f, (f16)0.f};   // (a00,a01)
                f16x2 accB = {(f16)0.f, (f16)0.f};   // (a10,a11)
                #pragma unroll
                for (int ky = 0; ky < 5; ++ky)
                    #pragma unroll
                    for (int kx = 0; kx < 5; ++kx) {
                        const uint wp = w1pk[c * 25 + ky * 5 + kx]; // uniform->sgpr
                        const f16x2 wv = __builtin_bit_cast(f16x2, wp);
                        accT += pr[ky * 5 + kx] * wv;        // v_pk_fma_f16
                        accB += pr[(ky + 1) * 5 + kx] * wv;
                    }
                const float q0 = fmaxf((float)accT[0], (float)accB[0]);
                const float q1 = fmaxf((float)accT[1], (float)accB[1]);
                ch[c] = (f16)fmaxf(fmaxf(q0, q1) + b1[c], 0.f);
            }
            f16x8 v0, v1;
            #pragma unroll
            for (int j = 0; j < 8; ++j) v0[j] = ch[j];
            v1[0] = ch[8]; v1[1] = ch[9];
            #pragma unroll
            for (int j = 2; j < 8; ++j) v1[j] = (f16)0.f;   // K-pad zeros
            unsigned char* dst = p1c + img * P1_IMG + py * P1_ROW + px * 32;
            *(f16x8*)(dst)      = v0;
            *(f16x8*)(dst + 16) = v1;
        }
    }

    // ---------- stage conv2 A-fragments (weights) into LDS --------------------
    for (int e = tid; e < 1000; e += THREADS) {
        const int s = e / 40;
        const int r = e - s * 40;
        const int oc = r >> 1, h = r & 1;
        f16x8 a;
        #pragma unroll
        for (int j = 0; j < 8; ++j) {
            const int ic = h * 8 + j;
            a[j] = (f16)(ic < 10 ? w2[(oc * 10 + ic) * 25 + s] : 0.f);
        }
        *(f16x8*)&u.af[e * 8] = a;
    }
    __syncthreads();

    // ---------- conv2 via mfma_f32_32x32x16_f16, s-outer, 2 tiles/wave --------
    const int cy = cM >> 3, cx = cM & 7;
    const int afoff = ((cM < 20 ? cM : 19) * 2 + hK) * 8;  // rows>=20 unused
    int bb[2];
    #pragma unroll
    for (int q = 0; q < 2; ++q) {
        const int t = wv_ * 2 + q, im = t >> 1, h2 = t & 1;
        bb[q] = im * P1_IMG + (4 * h2 + cy) * P1_ROW + cx * 32 + hK * 16;
    }
    f32x16 acc[2];
    #pragma unroll
    for (int q = 0; q < 2; ++q)
        #pragma unroll
        for (int r = 0; r < 16; ++r) acc[q][r] = 0.f;
    #pragma unroll 1
    for (int ky = 0; ky < 5; ++ky) {
        #pragma unroll
        for (int kx = 0; kx < 5; ++kx) {
            const f16x8 a = *(const f16x8*)&u.af[(ky * 5 + kx) * 320 + afoff];
            #pragma unroll
            for (int q = 0; q < 2; ++q) {
                const f16x8 b =
                    *(const f16x8*)(p1c + bb[q] + ky * P1_ROW + kx * 32);
                acc[q] = __builtin_amdgcn_mfma_f32_32x32x16_f16(a, b, acc[q],
                                                                0, 0, 0);
            }
        }
    }
    __syncthreads();   // af & p1c dead -> union may flip to p2/h1

    // ---------- epilogue: pool(shfl 1,8) + bias + relu -> u.s.p2 --------------
    #pragma unroll
    for (int q = 0; q < 2; ++q) {
        const int t = wv_ * 2 + q, im = t >> 1, h2 = t & 1;
        #pragma unroll
        for (int r = 0; r < 16; ++r) {
            const int m = (r & 3) + 8 * (r >> 2) + 4 * hK;
            float v = acc[q][r];
            v = fmaxf(v, __shfl_xor(v, 1, 64));
            v = fmaxf(v, __shfl_xor(v, 8, 64));
            if (m < 20 && (lane & 9) == 0) {
                const int py = 2 * h2 + (cM >> 4), px = cx >> 1;
                u.s.p2[im * 321 + m * 16 + py * 4 + px] = fmaxf(v + b2[m], 0.f);
            }
        }
    }
    __syncthreads();

    // ---------- fc1: 320->50 relu; lane=k, coalesced wl1, shuffle reduce ------
    {
        const int hbase = wv_ * 13;
        const int nh = (wv_ == 3) ? 11 : 13;       // 13+13+13+11 = 50
        for (int hi = 0; hi < nh; ++hi) {
            const int h = hbase + hi;
            float wrow[5];
            #pragma unroll
            for (int j = 0; j < 5; ++j)          // coalesced: k = lane + 64j
                wrow[j] = wl1[h * 320 + lane + 64 * j];
            for (int im = 0; im < IPB; ++im) {
                float s = 0.f;
                #pragma unroll
                for (int j = 0; j < 5; ++j)
                    s += u.s.p2[im * 321 + lane + 64 * j] * wrow[j];
                #pragma unroll
                for (int off = 32; off; off >>= 1)
                    s += __shfl_xor(s, off, 64);
                if (lane == 0)
                    u.s.h1[im * 51 + h] = fmaxf(s + bl1[h], 0.f);
            }
        }
    }
    __syncthreads();

    // ---------- fc2: 50->10 ---------------------------------------------------
    if (tid < IPB * 10) {
        const int im = tid / 10, o = tid % 10;
        const int imgo = min(blockIdx.x * IPB + im, batch - 1);
        float a = bl2[o];
        #pragma unroll
        for (int h = 0; h < 50; ++h)
            a += u.s.h1[im * 51 + h] * wl2[o * 50 + h];
        out[(size_t)imgo * 10 + o] = a;          // coalesced
    }
}

extern "C" void kernel_launch(void* const* d_in, const int* in_sizes, int n_in,
                              void* d_out, int out_size, void* d_ws, size_t ws_size,
                              hipStream_t stream) {
    const float* x   = (const float*)d_in[0];
    const float* w1  = (const float*)d_in[1];
    const float* b1  = (const float*)d_in[2];
    const float* w2  = (const float*)d_in[3];
    const float* b2  = (const float*)d_in[4];
    const float* wl1 = (const float*)d_in[5];
    const float* bl1 = (const float*)d_in[6];
    const float* wl2 = (const float*)d_in[7];
    const float* bl2 = (const float*)d_in[8];
    float* out = (float*)d_out;
    uint* w1pk = (uint*)d_ws;     // 250 packed (f16,f16) weight pairs

    const int batch = in_sizes[0] / 784;  // 8192
    pack_w1<<<1, 256, 0, stream>>>(w1, w1pk);
    const int grid = (batch + IPB - 1) / IPB;
    lenet_one<<<grid, THREADS, 0, stream>>>(x, w1pk, b1, w2, b2, wl1, bl1, wl2, bl2,
                                            out, batch);
}

// Round 10
// 138.374 us; speedup vs baseline: 1.9889x; 1.2754x over previous
//
#include <hip/hip_runtime.h>

#define THREADS 256
#define IPB 4   // images per block; grid = batch/4 = 2048

typedef _Float16 f16;
typedef _Float16 f16x2 __attribute__((ext_vector_type(2)));
typedef _Float16 f16x8 __attribute__((ext_vector_type(8)));
typedef float f32x4 __attribute__((ext_vector_type(4)));
typedef float f32x16 __attribute__((ext_vector_type(16)));
typedef unsigned int uint;

__device__ __forceinline__ f16x2 pkrtz(float a, float b) {
    return __builtin_bit_cast(f16x2, __builtin_amdgcn_cvt_pkrtz(a, b));
}
template<int CTRL>
__device__ __forceinline__ float dppmax(float v) {   // fmax with DPP-shuffled lane
    const int i = __builtin_bit_cast(int, v);
    const int s = __builtin_amdgcn_update_dpp(i, i, CTRL, 0xF, 0xF, true);
    return fmaxf(v, __builtin_bit_cast(float, s));
}

// p1 layout: [img][iy 12][ix 12][ic 16] f16. Row stride 400B; final row unpadded
// so img stride = 11*400+384 = 4784B. ic 10..15 zeros (K-pad).
#define P1_ROW 400
#define P1_IMG 4784

// d_ws layout: [0)      w1pk   250 x uint (dup f16 pairs)
//              [1024)   w2af   1000 x f16x8  (conv2 A-frags [s][oc*2+hK])
//              [17408)  wl1pk  2560 x f16x8  (fc1 A-frags [tile][s][lane])
__global__ void pack_weights(const float* __restrict__ w1,
                             const float* __restrict__ w2,
                             const float* __restrict__ wl1,
                             unsigned char* __restrict__ ws) {
    uint* w1pk  = (uint*)ws;
    f16x8* w2af = (f16x8*)(ws + 1024);
    f16x8* wl1pk = (f16x8*)(ws + 17408);
    const int gid = blockIdx.x * blockDim.x + threadIdx.x;
    const int gsz = gridDim.x * blockDim.x;
    for (int i = gid; i < 250; i += gsz) {
        const unsigned short u =
            __builtin_bit_cast(unsigned short, (f16)w1[i]);
        w1pk[i] = (uint)u | ((uint)u << 16);
    }
    for (int e = gid; e < 1000; e += gsz) {          // conv2 A-frags
        const int s = e / 40, r = e - s * 40;
        const int oc = r >> 1, h = r & 1;
        f16x8 a;
        #pragma unroll
        for (int j = 0; j < 8; ++j) {
            const int ic = h * 8 + j;
            a[j] = (f16)(ic < 10 ? w2[(oc * 10 + ic) * 25 + s] : 0.f);
        }
        w2af[e] = a;
    }
    for (int e = gid; e < 2560; e += gsz) {          // fc1 A-frags
        const int tile = e / 640, rem = e % 640;
        const int s = rem / 64, lane = rem % 64;
        const int m = lane & 15, quad = lane >> 4;
        const int hh = tile * 16 + m;
        f16x8 a;
        #pragma unroll
        for (int j = 0; j < 8; ++j)
            a[j] = (f16)(hh < 50 ? wl1[hh * 320 + s * 32 + quad * 8 + j] : 0.f);
        wl1pk[e] = a;
    }
}

// LDS: p1c 19136 + p2h 4*328*2=2624 + h1 4*52*4=832 = 22592 B -> 7 blocks/CU.
__global__ __launch_bounds__(THREADS, 6)
void lenet_one(const float* __restrict__ x,
               const unsigned char* __restrict__ ws, const float* __restrict__ b1,
               const float* __restrict__ b2,
               const float* __restrict__ bl1,
               const float* __restrict__ wl2, const float* __restrict__ bl2,
               float* __restrict__ out, int batch)
{
    __shared__ __align__(16) unsigned char p1c[IPB * P1_IMG];
    __shared__ __align__(16) f16 p2h[IPB * 328];  // [img][k 320 pad 328]
    __shared__ float h1[IPB * 52];                // [img][50 pad 52]

    const uint*  w1pk  = (const uint*)ws;
    const f16x8* w2af  = (const f16x8*)(ws + 1024);
    const f16x8* wl1pk = (const f16x8*)(ws + 17408);

    const int tid = threadIdx.x;
    const int lane = tid & 63;
    const int wv_ = tid >> 6;                 // wave id 0..3
    const int cM = lane & 31, hK = lane >> 5; // conv2 MFMA: row m=cM, K-half hK
    const int img = tid & 3;
    const int imgg = min(blockIdx.x * IPB + img, batch - 1);

    // ---------- conv1 (1->10ch) packed f16 + bias + relu + pool ---------------
    {
        const int grp = tid >> 2;                 // 0..63 position groups
        const float* xim = x + (size_t)imgg * 784;
        for (int pq = grp; pq < 144; pq += 64) {
            const int py = pq / 12, px = pq % 12;
            const float* xb = xim + (2 * py) * 28 + 2 * px;
            float win[36];
            #pragma unroll
            for (int r = 0; r < 6; ++r)
                #pragma unroll
                for (int cc = 0; cc < 6; ++cc)
                    win[r * 6 + cc] = xb[r * 28 + cc];
            f16x2 pr[30];                         // shifted pairs, reused x10 ch
            #pragma unroll
            for (int r = 0; r < 6; ++r)
                #pragma unroll
                for (int cc = 0; cc < 5; ++cc)
                    pr[r * 5 + cc] = pkrtz(win[r * 6 + cc], win[r * 6 + cc + 1]);
            f16 ch[10];
            #pragma unroll
            for (int c = 0; c < 10; ++c) {
                f16x2 accT = {(f16)0.f, (f16)0.f};
                f16x2 accB = {(f16)0.f, (f16)0.f};
                #pragma unroll
                for (int ky = 0; ky < 5; ++ky)
                    #pragma unroll
                    for (int kx = 0; kx < 5; ++kx) {
                        const uint wp = w1pk[c * 25 + ky * 5 + kx]; // sgpr
                        const f16x2 wv = __builtin_bit_cast(f16x2, wp);
                        accT += pr[ky * 5 + kx] * wv;        // v_pk_fma_f16
                        accB += pr[(ky + 1) * 5 + kx] * wv;
                    }
                const float q0 = fmaxf((float)accT[0], (float)accB[0]);
                const float q1 = fmaxf((float)accT[1], (float)accB[1]);
                ch[c] = (f16)fmaxf(fmaxf(q0, q1) + b1[c], 0.f);
            }
            f16x8 v0, v1;
            #pragma unroll
            for (int j = 0; j < 8; ++j) v0[j] = ch[j];
            v1[0] = ch[8]; v1[1] = ch[9];
            #pragma unroll
            for (int j = 2; j < 8; ++j) v1[j] = (f16)0.f;   // K-pad zeros
            unsigned char* dst = p1c + img * P1_IMG + py * P1_ROW + px * 32;
            *(f16x8*)(dst)      = v0;
            *(f16x8*)(dst + 16) = v1;
        }
    }
    __syncthreads();

    // ---------- conv2 via mfma_f32_32x32x16_f16; A-frags from global ----------
    {
        const int cy = cM >> 3, cx = cM & 7;
        const int afoff = (cM < 20 ? cM : 19) * 2 + hK;
        int bb[2];
        #pragma unroll
        for (int q = 0; q < 2; ++q) {
            const int t = wv_ * 2 + q, im = t >> 1, h2 = t & 1;
            bb[q] = im * P1_IMG + (4 * h2 + cy) * P1_ROW + cx * 32 + hK * 16;
        }
        f32x16 acc[2];
        #pragma unroll
        for (int q = 0; q < 2; ++q)
            #pragma unroll
            for (int r = 0; r < 16; ++r) acc[q][r] = 0.f;
        #pragma unroll 1
        for (int ky = 0; ky < 5; ++ky) {
            #pragma unroll
            for (int kx = 0; kx < 5; ++kx) {
                const f16x8 a = w2af[(ky * 5 + kx) * 40 + afoff];
                #pragma unroll
                for (int q = 0; q < 2; ++q) {
                    const f16x8 b =
                        *(const f16x8*)(p1c + bb[q] + ky * P1_ROW + kx * 32);
                    acc[q] = __builtin_amdgcn_mfma_f32_32x32x16_f16(a, b, acc[q],
                                                                    0, 0, 0);
                }
            }
        }
        // epilogue: pool via DPP (xor1 = quad_perm(1,0,3,2)=0xB1; xor8 = row_ror:8)
        #pragma unroll
        for (int q = 0; q < 2; ++q) {
            const int t = wv_ * 2 + q, im = t >> 1, h2 = t & 1;
            #pragma unroll
            for (int r = 0; r < 16; ++r) {
                const int m = (r & 3) + 8 * (r >> 2) + 4 * hK;
                float v = acc[q][r];
                v = dppmax<0xB1>(v);
                v = dppmax<0x128>(v);
                if (m < 20 && (lane & 9) == 0) {
                    const int py = 2 * h2 + (cM >> 4), px = cx >> 1;
                    p2h[im * 328 + m * 16 + py * 4 + px] =
                        (f16)fmaxf(v + b2[m], 0.f);
                }
            }
        }
    }
    __syncthreads();

    // ---------- fc1 via mfma_f32_16x16x32_f16: M=h tile/wave, N=img, K=320 ----
    {
        const int n = lane & 15, quad = lane >> 4;
        f32x4 facc = {0.f, 0.f, 0.f, 0.f};
        #pragma unroll 1
        for (int s = 0; s < 10; ++s) {
            const f16x8 a = wl1pk[(wv_ * 10 + s) * 64 + lane];  // coalesced b128
            f16x8 b = {};
            if (n < IPB)
                b = *(const f16x8*)(p2h + n * 328 + s * 32 + quad * 8);
            facc = __builtin_amdgcn_mfma_f32_16x16x32_f16(a, b, facc, 0, 0, 0);
        }
        if (n < IPB) {
            #pragma unroll
            for (int r = 0; r < 4; ++r) {
                const int h = wv_ * 16 + quad * 4 + r;
                if (h < 50)
                    h1[n * 52 + h] = fmaxf(facc[r] + bl1[h], 0.f);
            }
        }
    }
    __syncthreads();

    // ---------- fc2: 50->10 ---------------------------------------------------
    if (tid < IPB * 10) {
        const int im = tid / 10, o = tid % 10;
        const int imgo = min(blockIdx.x * IPB + im, batch - 1);
        float a = bl2[o];
        #pragma unroll
        for (int h = 0; h < 50; ++h)
            a += h1[im * 52 + h] * wl2[o * 50 + h];
        out[(size_t)imgo * 10 + o] = a;          // coalesced
    }
}

extern "C" void kernel_launch(void* const* d_in, const int* in_sizes, int n_in,
                              void* d_out, int out_size, void* d_ws, size_t ws_size,
                              hipStream_t stream) {
    const float* x   = (const float*)d_in[0];
    const float* w1  = (const float*)d_in[1];
    const float* b1  = (const float*)d_in[2];
    const float* w2  = (const float*)d_in[3];
    const float* b2  = (const float*)d_in[4];
    const float* wl1 = (const float*)d_in[5];
    const float* bl1 = (const float*)d_in[6];
    const float* wl2 = (const float*)d_in[7];
    const float* bl2 = (const float*)d_in[8];
    float* out = (float*)d_out;
    unsigned char* ws = (unsigned char*)d_ws;   // 58 KB of packed weights

    const int batch = in_sizes[0] / 784;  // 8192
    pack_weights<<<16, 256, 0, stream>>>(w1, w2, wl1, ws);
    const int grid = (batch + IPB - 1) / IPB;
    lenet_one<<<grid, THREADS, 0, stream>>>(x, ws, b1, b2, bl1, wl2, bl2,
                                            out, batch);
}